// Round 14
// baseline (892.564 us; speedup 1.0000x reference)
//
#include <hip/hip_runtime.h>

// GLATE: 3-layer GraphSAGE encoder x2 graphs.
// Round 14: big GEMM 256x256 with BK=32 -> 64KB staging LDS -> 2 blocks/CU.
// Theory: the per-K-step vmcnt(0) drain idles the CU at 1 block/CU; a second
// resident block's MFMA covers the drain (m114 inter-block overlap).
// Everything else unchanged from round 13 (834us).

#define NN 50000
#define N2 100000            // batched nodes
#define NE 400000
#define E2 800000            // batched edges
#define DIN 128
#define DH 512
#define MPAD 100352          // 784*128 = 392*256

typedef __attribute__((ext_vector_type(4))) float f32x4;
typedef __attribute__((ext_vector_type(8))) short bf16x8;
typedef unsigned short u16;

__device__ __forceinline__ u16 f2bf(float f) {
    unsigned u = __float_as_uint(f);
    unsigned r = (u + 0x7fff + ((u >> 16) & 1)) >> 16;   // RNE
    return (u16)r;
}
__device__ __forceinline__ float bf2f(u16 b) {
    return __uint_as_float((unsigned)b << 16);
}

__device__ __forceinline__ void gload16(const void* g, void* l) {
    __builtin_amdgcn_global_load_lds(
        (const __attribute__((address_space(1))) unsigned int*)g,
        (__attribute__((address_space(3))) unsigned int*)l, 16, 0, 0);
}

// ---------------- CSR build (batched: graph-2 nodes offset by NN) ----------------

__global__ void k_zero_int(int* __restrict__ p, int n) {
    int i = blockIdx.x * 256 + threadIdx.x;
    if (i < n) p[i] = 0;
}

__global__ void k_deg(const int* __restrict__ dst, int* __restrict__ deg, int E, int off) {
    int e = blockIdx.x * 256 + threadIdx.x;
    if (e < E) atomicAdd(&deg[dst[e] + off], 1);
}

__global__ __launch_bounds__(1024) void k_scan1(
        const int* __restrict__ deg, int* __restrict__ rowptr,
        int* __restrict__ bsum, int n) {
    __shared__ int buf[1024];
    int i = blockIdx.x * 1024 + threadIdx.x;
    int v = (i < n) ? deg[i] : 0;
    buf[threadIdx.x] = v;
    __syncthreads();
    for (int off = 1; off < 1024; off <<= 1) {
        int t = (threadIdx.x >= off) ? buf[threadIdx.x - off] : 0;
        __syncthreads();
        buf[threadIdx.x] += t;
        __syncthreads();
    }
    if (i < n) rowptr[i] = buf[threadIdx.x] - v;
    if (threadIdx.x == 1023) bsum[blockIdx.x] = buf[1023];
}

__global__ __launch_bounds__(128) void k_scan2(int* __restrict__ bsum, int nb) {
    __shared__ int buf[128];
    int v = (threadIdx.x < nb) ? bsum[threadIdx.x] : 0;
    buf[threadIdx.x] = v;
    __syncthreads();
    for (int off = 1; off < 128; off <<= 1) {
        int t = (threadIdx.x >= off) ? buf[threadIdx.x - off] : 0;
        __syncthreads();
        buf[threadIdx.x] += t;
        __syncthreads();
    }
    if (threadIdx.x < nb) bsum[threadIdx.x] = buf[threadIdx.x] - v;
}

__global__ void k_scan3(int* __restrict__ rowptr, const int* __restrict__ bsum,
                        int* __restrict__ cursor, int n, int total) {
    int i = blockIdx.x * 256 + threadIdx.x;
    if (i < n) {
        int v = rowptr[i] + bsum[i >> 10];
        rowptr[i] = v;
        cursor[i] = v;
    }
    if (i == 0) rowptr[n] = total;
}

__global__ void k_fill(const int* __restrict__ src, const int* __restrict__ dst,
                       int* __restrict__ cursor, int* __restrict__ col, int E, int off) {
    int e = blockIdx.x * 256 + threadIdx.x;
    if (e < E) {
        int p = atomicAdd(&cursor[dst[e] + off], 1);
        col[p] = src[e] + off;
    }
}

// ---------------- f32 -> bf16 cast ----------------

__global__ void k_cast_bf(const float* __restrict__ x, u16* __restrict__ o, int n) {
    int i = (blockIdx.x * 256 + threadIdx.x) * 4;
    if (i + 3 < n) {
        float4 v = *(const float4*)&x[i];
        o[i + 0] = f2bf(v.x); o[i + 1] = f2bf(v.y);
        o[i + 2] = f2bf(v.z); o[i + 3] = f2bf(v.w);
    } else {
        for (int j = i; j < n; ++j) o[j] = f2bf(x[j]);
    }
}

// ---------------- weight transpose + cast: W[K,N] f32 -> Wt[N,K] bf16 ----------------

__global__ void k_wt(const float* __restrict__ W, u16* __restrict__ Wt, int K, int N) {
    __shared__ float t[32][33];
    int bn = blockIdx.x * 32;
    int bk = blockIdx.y * 32;
    int x = threadIdx.x;
    int y = threadIdx.y;
    for (int i = y; i < 32; i += 8) t[i][x] = W[(size_t)(bk + i) * N + bn + x];
    __syncthreads();
    for (int i = y; i < 32; i += 8)
        Wt[(size_t)(bn + i) * K + bk + x] = f2bf(t[x][i]);
}

// ---------------- mean aggregation over CSR, bf16 in/out, f32 accum ----------------
// 4-deep software pipeline (round-13 verified)

template<int D>
__global__ __launch_bounds__(256) void k_agg_bf(
        const u16* __restrict__ x, const int* __restrict__ rowptr,
        const int* __restrict__ col, u16* __restrict__ mean, int n) {
    int node = blockIdx.x * 4 + (threadIdx.x >> 6);
    if (node >= n) return;
    int lane = threadIdx.x & 63;
    int s = rowptr[node], e = rowptr[node + 1];
    float inv = (e > s) ? 1.0f / (float)(e - s) : 0.0f;
    if (D == 512) {
        float acc[8] = {};
        const u16* xp = x + lane * 8;
        auto accum = [&](uint4 v) {
            unsigned w[4] = { v.x, v.y, v.z, v.w };
#pragma unroll
            for (int q = 0; q < 4; ++q) {
                acc[2 * q + 0] += bf2f((u16)(w[q] & 0xffff));
                acc[2 * q + 1] += bf2f((u16)(w[q] >> 16));
            }
        };
        int j = s;
        for (; j + 4 <= e; j += 4) {
            int r0 = col[j], r1 = col[j + 1], r2 = col[j + 2], r3 = col[j + 3];
            uint4 v0 = *(const uint4*)(xp + (size_t)r0 * D);
            uint4 v1 = *(const uint4*)(xp + (size_t)r1 * D);
            uint4 v2 = *(const uint4*)(xp + (size_t)r2 * D);
            uint4 v3 = *(const uint4*)(xp + (size_t)r3 * D);
            accum(v0); accum(v1); accum(v2); accum(v3);
        }
        for (; j < e; ++j) {
            int r = col[j];
            accum(*(const uint4*)(xp + (size_t)r * D));
        }
        unsigned o[4];
#pragma unroll
        for (int q = 0; q < 4; ++q)
            o[q] = (unsigned)f2bf(acc[2 * q] * inv) |
                   ((unsigned)f2bf(acc[2 * q + 1] * inv) << 16);
        *(uint4*)(mean + (size_t)node * D + lane * 8) = make_uint4(o[0], o[1], o[2], o[3]);
    } else {  // D == 128
        float a0 = 0.f, a1 = 0.f;
        const u16* xp = x + lane * 2;
        int j = s;
        for (; j + 4 <= e; j += 4) {
            int r0 = col[j], r1 = col[j + 1], r2 = col[j + 2], r3 = col[j + 3];
            unsigned v0 = *(const unsigned*)(xp + (size_t)r0 * D);
            unsigned v1 = *(const unsigned*)(xp + (size_t)r1 * D);
            unsigned v2 = *(const unsigned*)(xp + (size_t)r2 * D);
            unsigned v3 = *(const unsigned*)(xp + (size_t)r3 * D);
            a0 += bf2f((u16)(v0 & 0xffff)) + bf2f((u16)(v1 & 0xffff))
                + bf2f((u16)(v2 & 0xffff)) + bf2f((u16)(v3 & 0xffff));
            a1 += bf2f((u16)(v0 >> 16)) + bf2f((u16)(v1 >> 16))
                + bf2f((u16)(v2 >> 16)) + bf2f((u16)(v3 >> 16));
        }
        for (; j < e; ++j) {
            unsigned v = *(const unsigned*)(xp + (size_t)col[j] * D);
            a0 += bf2f((u16)(v & 0xffff));
            a1 += bf2f((u16)(v >> 16));
        }
        unsigned o = (unsigned)f2bf(a0 * inv) | ((unsigned)f2bf(a1 * inv) << 16);
        *(unsigned*)(mean + (size_t)node * D + lane * 2) = o;
    }
}

#define MFMA_BF16(a, b, c) __builtin_amdgcn_mfma_f32_16x16x32_bf16(a, b, c, 0, 0, 0)

// ---------------- layer-1 fused kernel (round-8, unchanged) ----------------

__global__ __launch_bounds__(256) void k_l1f(
        const u16* __restrict__ X, const u16* __restrict__ Mn,
        const u16* __restrict__ Wr1, const u16* __restrict__ Wl1,
        const u16* __restrict__ Ww,  const u16* __restrict__ Ww2,
        const float* __restrict__ bl1, const float* __restrict__ Wb,
        const float* __restrict__ W2b, const float* __restrict__ prelu_a,
        u16* xin2, u16* xp3, int M) {
    __shared__ __align__(16) char SH[65536];

    int tid = threadIdx.x;
    int wid = tid >> 6, lane = tid & 63;
    int wm = wid >> 1, wn = wid & 1;
    const int lm = lane & 15;
    const int kq = lane >> 4;

    int nwg = gridDim.x;
    int q = nwg >> 3;
    int swz = (blockIdx.x & 7) * q + (blockIdx.x >> 3);
    int m0 = (swz >> 3) * 128;
    int n0 = (swz & 7) * 64;

    f32x4 acch[4][2], accw[4][2], accw2[4][2];
#pragma unroll
    for (int mi = 0; mi < 4; ++mi)
#pragma unroll
        for (int ni = 0; ni < 2; ++ni) {
            acch[mi][ni] = (f32x4){0.f, 0.f, 0.f, 0.f};
            accw[mi][ni] = (f32x4){0.f, 0.f, 0.f, 0.f};
            accw2[mi][ni] = (f32x4){0.f, 0.f, 0.f, 0.f};
        }

    const u16* Bmat[4] = { Wr1, Wl1, Ww, Ww2 };

    auto stage = [&](int buf, int s) {
        int k0 = s * 32;
        char* base = SH + buf * 32768;
#pragma unroll
        for (int i = 0; i < 2; ++i) {
            int f = tid + i * 256;
            int row = f >> 2, g = f & 3;
            int gs = g ^ (row & 3);
            gload16(X + (size_t)(m0 + row) * DIN + k0 + gs * 8,
                    base + i * 4096 + wid * 1024);
        }
#pragma unroll
        for (int i = 0; i < 2; ++i) {
            int f = tid + i * 256;
            int row = f >> 2, g = f & 3;
            int gs = g ^ (row & 3);
            gload16(Mn + (size_t)(m0 + row) * DIN + k0 + gs * 8,
                    base + 8192 + i * 4096 + wid * 1024);
        }
#pragma unroll
        for (int m = 0; m < 4; ++m) {
            int row = tid >> 2, g = tid & 3;
            int gs = g ^ (row & 3);
            gload16(Bmat[m] + (size_t)(n0 + row) * DIN + k0 + gs * 8,
                    base + 16384 + m * 4096 + wid * 1024);
        }
    };

    stage(0, 0);
    __syncthreads();

    int cur = 0;
#pragma unroll 1
    for (int s = 0; s < 4; ++s) {
        if (s + 1 < 4) stage(cur ^ 1, s + 1);

        const char* base = SH + cur * 32768;
        bf16x8 ax[4], am[4];
#pragma unroll
        for (int mi = 0; mi < 4; ++mi) {
            int row = wm * 64 + mi * 16 + lm;
            int g = kq ^ (row & 3);
            ax[mi] = *(const bf16x8*)(base + row * 64 + g * 16);
            am[mi] = *(const bf16x8*)(base + 8192 + row * 64 + g * 16);
        }
#pragma unroll
        for (int m = 0; m < 4; ++m) {
            bf16x8 bfr[2];
#pragma unroll
            for (int ni = 0; ni < 2; ++ni) {
                int row = wn * 32 + ni * 16 + lm;
                int g = kq ^ (row & 3);
                bfr[ni] = *(const bf16x8*)(base + 16384 + m * 4096 + row * 64 + g * 16);
            }
#pragma unroll
            for (int mi = 0; mi < 4; ++mi)
#pragma unroll
                for (int ni = 0; ni < 2; ++ni) {
                    if (m == 0) acch[mi][ni]  = MFMA_BF16(ax[mi], bfr[ni], acch[mi][ni]);
                    if (m == 1) acch[mi][ni]  = MFMA_BF16(am[mi], bfr[ni], acch[mi][ni]);
                    if (m == 2) accw[mi][ni]  = MFMA_BF16(ax[mi], bfr[ni], accw[mi][ni]);
                    if (m == 3) accw2[mi][ni] = MFMA_BF16(ax[mi], bfr[ni], accw2[mi][ni]);
                }
        }
        __syncthreads();
        cur ^= 1;
    }

    float aslope = *prelu_a;
    float blv[2], wbv[2], w2bv[2];
#pragma unroll
    for (int ni = 0; ni < 2; ++ni) {
        int col = n0 + wn * 32 + ni * 16 + lm;
        blv[ni] = bl1[col]; wbv[ni] = Wb[col]; w2bv[ni] = W2b[col];
    }
    char* T = SH + wid * 4608;
#pragma unroll
    for (int pass = 0; pass < 2; ++pass) {
#pragma unroll
        for (int mi = 0; mi < 4; ++mi)
#pragma unroll
            for (int ni = 0; ni < 2; ++ni)
#pragma unroll
                for (int r2 = 0; r2 < 4; ++r2) {
                    float h = acch[mi][ni][r2] + blv[ni];
                    h = (h >= 0.f) ? h : aslope * h;
                    float v = (pass == 0) ? h + accw[mi][ni][r2] + wbv[ni]
                                          : h + accw2[mi][ni][r2] + w2bv[ni];
                    ((u16*)(T + (mi * 16 + kq * 4 + r2) * 72))[ni * 16 + lm] = f2bf(v);
                }
        u16* O = pass ? xp3 : xin2;
#pragma unroll
        for (int it = 0; it < 4; ++it) {
            int lrow = it * 16 + (lane >> 2), seg = lane & 3;
            uint4 d = *(const uint4*)(T + lrow * 72 + seg * 16);
            int grow = m0 + wm * 64 + lrow;
            if (grow < M)
                *(uint4*)(O + (size_t)grow * DH + n0 + wn * 32 + seg * 8) = d;
        }
    }
}

// ---------------- big MFMA GEMM: 256x256 tile, BK=32, 8 waves, 2-phase ----------------
// 64KB staging LDS -> 2 blocks/CU; drain of one block overlaps compute of the other.

template<bool ADDEND, bool OUTF32>
__global__ __launch_bounds__(512) void k_mfma(
        const u16* __restrict__ A1, const u16* __restrict__ B1t,
        const u16* __restrict__ A2, const u16* __restrict__ B2t,
        const float* __restrict__ bias, const u16* addend,
        const float* __restrict__ prelu_a,
        float* Cf, u16* Cb, int M) {
    constexpr int MI = 8;
    // staging: A bufs @0/@16K, B bufs @32K/@48K (64KB); epilogue 8x9216=72KB
    __shared__ __align__(16) char SH[73728];

    constexpr int NS = 32;                      // (512+512)/32

    int tid = threadIdx.x;
    int wid = tid >> 6, lane = tid & 63;
    int wm = wid >> 2, wn = wid & 3;            // 2m x 4n
    const int lm = lane & 15;
    const int kq = lane >> 4;

    int nwg = gridDim.x;                        // 784, %8==0
    int q = nwg >> 3;
    int swz = (blockIdx.x & 7) * q + (blockIdx.x >> 3);
    int m0 = (swz >> 1) * 256;
    int n0 = (swz & 1) * 256;

    f32x4 acc[MI][4];
#pragma unroll
    for (int mi = 0; mi < MI; ++mi)
#pragma unroll
        for (int ni = 0; ni < 4; ++ni)
            acc[mi][ni] = (f32x4){0.f, 0.f, 0.f, 0.f};

    auto stage = [&](int buf, int s) {
        const u16* A; const u16* Bt; int k0;
        if (s < 16) { A = A1; Bt = B1t; k0 = s * 32; }
        else        { A = A2; Bt = B2t; k0 = (s - 16) * 32; }
#pragma unroll
        for (int i = 0; i < 2; ++i) {           // A: 256 rows x 4 granules = 16KB
            int f = tid + i * 512;
            int row = f >> 2, g = f & 3;
            int gs = g ^ (row & 3);
            gload16(A + (size_t)(m0 + row) * DH + k0 + gs * 8,
                    SH + buf * 16384 + i * 8192 + wid * 1024);
        }
#pragma unroll
        for (int i = 0; i < 2; ++i) {           // B: 256 rows x 4 granules = 16KB
            int f = tid + i * 512;
            int row = f >> 2, g = f & 3;
            int gs = g ^ (row & 3);
            gload16(Bt + (size_t)(n0 + row) * DH + k0 + gs * 8,
                    SH + 32768 + buf * 16384 + i * 8192 + wid * 1024);
        }
    };

    stage(0, 0);
    __syncthreads();

    int cur = 0;
#pragma unroll 1
    for (int s = 0; s < NS; ++s) {
        if (s + 1 < NS) stage(cur ^ 1, s + 1);  // issue next tile early

        const char* Ab = SH + cur * 16384;
        const char* Bb = SH + 32768 + cur * 16384;
        bf16x8 af[MI], bfr[4];
#pragma unroll
        for (int mi = 0; mi < MI; ++mi) {
            int row = wm * 128 + mi * 16 + lm;
            int g = kq ^ (row & 3);
            af[mi] = *(const bf16x8*)(Ab + row * 64 + g * 16);
        }
#pragma unroll
        for (int ni = 0; ni < 4; ++ni) {
            int row = wn * 64 + ni * 16 + lm;
            int g = kq ^ (row & 3);
            bfr[ni] = *(const bf16x8*)(Bb + row * 64 + g * 16);
        }
#pragma unroll
        for (int mi = 0; mi < MI; ++mi)
#pragma unroll
            for (int ni = 0; ni < 4; ++ni)
                acc[mi][ni] = MFMA_BF16(af[mi], bfr[ni], acc[mi][ni]);

        __syncthreads();                        // drains stage(s+1) + barrier
        cur ^= 1;
    }

    // ---- coalesced epilogue via per-wave LDS region ----
    float aslope = *prelu_a;
    char* EPW = SH + wid * 9216;
    float bv[4];
#pragma unroll
    for (int ni = 0; ni < 4; ++ni)
        bv[ni] = bias[n0 + wn * 64 + ni * 16 + lm];

    if (!OUTF32) {
        u16* T = (u16*)EPW;
#pragma unroll
        for (int sp = 0; sp < 2; ++sp) {
#pragma unroll
            for (int mq = 0; mq < 4; ++mq) {
                int mi = sp * 4 + mq;
#pragma unroll
                for (int ni = 0; ni < 4; ++ni)
#pragma unroll
                    for (int r2 = 0; r2 < 4; ++r2) {
                        float v = acc[mi][ni][r2] + bv[ni];
                        v = (v >= 0.f) ? v : aslope * v;
                        T[(mq * 16 + kq * 4 + r2) * 72 + ni * 16 + lm] = f2bf(v);
                    }
            }
#pragma unroll
            for (int it = 0; it < 8; ++it) {
                int lrow = it * 8 + (lane >> 3);
                int grow = m0 + wm * 128 + sp * 64 + lrow;
                uint4 d = *(const uint4*)(T + lrow * 72 + (lane & 7) * 8);
                if (grow < M) {
                    size_t off = (size_t)grow * DH + n0 + wn * 64 + (lane & 7) * 8;
                    if (ADDEND) {
                        uint4 ad = *(const uint4*)(addend + off);
                        unsigned* dp = (unsigned*)&d;
                        const unsigned* ap = (const unsigned*)&ad;
#pragma unroll
                        for (int qq = 0; qq < 4; ++qq) {
                            float lo = bf2f((u16)(dp[qq] & 0xffff)) + bf2f((u16)(ap[qq] & 0xffff));
                            float hi = bf2f((u16)(dp[qq] >> 16)) + bf2f((u16)(ap[qq] >> 16));
                            dp[qq] = (unsigned)f2bf(lo) | ((unsigned)f2bf(hi) << 16);
                        }
                    }
                    *(uint4*)(Cb + off) = d;
                }
            }
        }
    } else {
        float* T = (float*)EPW;
#pragma unroll
        for (int sp = 0; sp < 4; ++sp) {
#pragma unroll
            for (int mq = 0; mq < 2; ++mq) {
                int mi = sp * 2 + mq;
#pragma unroll
                for (int ni = 0; ni < 4; ++ni)
#pragma unroll
                    for (int r2 = 0; r2 < 4; ++r2) {
                        float v = acc[mi][ni][r2] + bv[ni];
                        v = (v >= 0.f) ? v : aslope * v;
                        T[(mq * 16 + kq * 4 + r2) * 68 + ni * 16 + lm] = v;
                    }
            }
#pragma unroll
            for (int it = 0; it < 8; ++it) {
                int lrow = it * 4 + (lane >> 4);
                int grow = m0 + wm * 128 + sp * 32 + lrow;
                float4 d = *(const float4*)(T + lrow * 68 + (lane & 15) * 4);
                if (grow < M)
                    *(float4*)(Cf + (size_t)grow * DH + n0 + wn * 64 + (lane & 15) * 4) = d;
            }
        }
    }
}

// ---------------- launch ----------------

extern "C" void kernel_launch(void* const* d_in, const int* in_sizes, int n_in,
                              void* d_out, int out_size, void* d_ws, size_t ws_size,
                              hipStream_t stream) {
    const float* x1 = (const float*)d_in[0];
    const float* x2 = (const float*)d_in[1];
    const int* ei1 = (const int*)d_in[2];
    const int* ei2 = (const int*)d_in[3];
    const float* l1_Wl = (const float*)d_in[4];
    const float* l1_bl = (const float*)d_in[5];
    const float* l1_Wr = (const float*)d_in[6];
    const float* l2_Wl = (const float*)d_in[7];
    const float* l2_bl = (const float*)d_in[8];
    const float* l2_Wr = (const float*)d_in[9];
    const float* l3_Wl = (const float*)d_in[10];
    const float* l3_bl = (const float*)d_in[11];
    const float* l3_Wr = (const float*)d_in[12];
    const float* W_w = (const float*)d_in[13];
    const float* W_b = (const float*)d_in[14];
    const float* W2_w = (const float*)d_in[15];
    const float* W2_b = (const float*)d_in[16];
    const float* prelu_a = (const float*)d_in[17];

    // ---- workspace layout ----
    u16* wb = (u16*)d_ws;
    u16* Wr1t = wb;                        // [512,128]
    u16* Wl1t = Wr1t + 512 * 128;
    u16* Wwt  = Wl1t + 512 * 128;
    u16* W2wt = Wwt  + 512 * 128;
    u16* Wl2t = W2wt + 512 * 128;          // [512,512]
    u16* Wr2t = Wl2t + 512 * 512;
    u16* Wl3t = Wr2t + 512 * 512;
    u16* Wr3t = Wl3t + 512 * 512;
    u16* x_bf    = Wr3t + 512 * 512;               // [MPAD,128]
    u16* mean_bf = x_bf + (size_t)MPAD * DIN;      // [MPAD,512]
    u16* xin2_bf = mean_bf + (size_t)MPAD * DH;    // [MPAD,512]
    u16* xp3_bf  = xin2_bf + (size_t)MPAD * DH;    // [MPAD,512]; xin3 aliases this
    int* iws    = (int*)(xp3_bf + (size_t)MPAD * DH);
    int* deg    = iws;                     // N2
    int* rowptr = iws + N2;                // N2+1
    int* cursor = iws + 2 * N2 + 1;        // N2
    int* bsum   = iws + 3 * N2 + 1;        // 128
    int* colx   = iws + 3 * N2 + 129;      // 2E

    float* out = (float*)d_out;

    // ---- weight transposes (once) ----
    dim3 wtb(32, 8);
    k_wt<<<dim3(16, 4),  wtb, 0, stream>>>(l1_Wr, Wr1t, DIN, DH);
    k_wt<<<dim3(16, 4),  wtb, 0, stream>>>(l1_Wl, Wl1t, DIN, DH);
    k_wt<<<dim3(16, 4),  wtb, 0, stream>>>(W_w,  Wwt,  DIN, DH);
    k_wt<<<dim3(16, 4),  wtb, 0, stream>>>(W2_w, W2wt, DIN, DH);
    k_wt<<<dim3(16, 16), wtb, 0, stream>>>(l2_Wl, Wl2t, DH, DH);
    k_wt<<<dim3(16, 16), wtb, 0, stream>>>(l2_Wr, Wr2t, DH, DH);
    k_wt<<<dim3(16, 16), wtb, 0, stream>>>(l3_Wl, Wl3t, DH, DH);
    k_wt<<<dim3(16, 16), wtb, 0, stream>>>(l3_Wr, Wr3t, DH, DH);

    // ---- batched CSR over 2N nodes (hierarchical scan) ----
    const int NB = (N2 + 1023) / 1024;     // 98
    k_zero_int<<<(N2 + 255) / 256, 256, 0, stream>>>(deg, N2);
    k_deg<<<(NE + 255) / 256, 256, 0, stream>>>(ei1 + NE, deg, NE, 0);
    k_deg<<<(NE + 255) / 256, 256, 0, stream>>>(ei2 + NE, deg, NE, NN);
    k_scan1<<<NB, 1024, 0, stream>>>(deg, rowptr, bsum, N2);
    k_scan2<<<1, 128, 0, stream>>>(bsum, NB);
    k_scan3<<<(N2 + 255) / 256, 256, 0, stream>>>(rowptr, bsum, cursor, N2, E2);
    k_fill<<<(NE + 255) / 256, 256, 0, stream>>>(ei1, ei1 + NE, cursor, colx, NE, 0);
    k_fill<<<(NE + 255) / 256, 256, 0, stream>>>(ei2, ei2 + NE, cursor, colx, NE, NN);

    // ---- features -> bf16 (both graphs into one buffer) ----
    k_cast_bf<<<(NN * DIN / 4 + 255) / 256, 256, 0, stream>>>(x1, x_bf, NN * DIN);
    k_cast_bf<<<(NN * DIN / 4 + 255) / 256, 256, 0, stream>>>(x2, x_bf + (size_t)NN * DIN, NN * DIN);

    const int nwgL1 = (MPAD / 128) * 8;    // 6272
    const int nwgB  = (MPAD / 256) * 2;    // 784
    const int aggGrid = (N2 + 3) / 4;      // 25000

    // layer 1: agg(D=128) + fused triple GEMM -> xin2, xp3  (H in registers)
    k_agg_bf<DIN><<<aggGrid, 256, 0, stream>>>(x_bf, rowptr, colx, mean_bf, N2);
    k_l1f<<<nwgL1, 256, 0, stream>>>(x_bf, mean_bf, Wr1t, Wl1t, Wwt, W2wt,
                                     l1_bl, W_b, W2_b, prelu_a, xin2_bf, xp3_bf, N2);

    // layer 2: agg(D=512) + GEMM; xin3 written in-place over xp3 (addend)
    k_agg_bf<DH><<<aggGrid, 256, 0, stream>>>(xin2_bf, rowptr, colx, mean_bf, N2);
    k_mfma<true, false><<<nwgB, 512, 0, stream>>>(
        mean_bf, Wl2t, xin2_bf, Wr2t, l2_bl, xp3_bf, prelu_a, nullptr, xp3_bf, N2);

    // layer 3: agg(D=512) + GEMM -> f32 out (z1|z2 = batched layout)
    k_agg_bf<DH><<<aggGrid, 256, 0, stream>>>(xp3_bf, rowptr, colx, mean_bf, N2);
    k_mfma<false, true><<<nwgB, 512, 0, stream>>>(
        mean_bf, Wl3t, xp3_bf, Wr3t, l3_bl, nullptr, prelu_a, out, nullptr, N2);
}

// Round 15
// 832.431 us; speedup vs baseline: 1.0722x; 1.0722x over previous
//
#include <hip/hip_runtime.h>

// GLATE: 3-layer GraphSAGE encoder x2 graphs.
// Round 15: big GEMM -> m97-proven 128x128/BK32/4-wave geometry + coalesced
// epilogue; 36KB LDS -> 4 blocks/CU so inter-block overlap (m114/m103) covers
// the per-K-step drain. Rest identical to round 13 (834us verified).

#define NN 50000
#define N2 100000            // batched nodes
#define NE 400000
#define E2 800000            // batched edges
#define DIN 128
#define DH 512
#define MPAD 100352          // 784*128 = 392*256

typedef __attribute__((ext_vector_type(4))) float f32x4;
typedef __attribute__((ext_vector_type(8))) short bf16x8;
typedef unsigned short u16;

__device__ __forceinline__ u16 f2bf(float f) {
    unsigned u = __float_as_uint(f);
    unsigned r = (u + 0x7fff + ((u >> 16) & 1)) >> 16;   // RNE
    return (u16)r;
}
__device__ __forceinline__ float bf2f(u16 b) {
    return __uint_as_float((unsigned)b << 16);
}

__device__ __forceinline__ void gload16(const void* g, void* l) {
    __builtin_amdgcn_global_load_lds(
        (const __attribute__((address_space(1))) unsigned int*)g,
        (__attribute__((address_space(3))) unsigned int*)l, 16, 0, 0);
}

// ---------------- CSR build (batched: graph-2 nodes offset by NN) ----------------

__global__ void k_zero_int(int* __restrict__ p, int n) {
    int i = blockIdx.x * 256 + threadIdx.x;
    if (i < n) p[i] = 0;
}

__global__ void k_deg(const int* __restrict__ dst, int* __restrict__ deg, int E, int off) {
    int e = blockIdx.x * 256 + threadIdx.x;
    if (e < E) atomicAdd(&deg[dst[e] + off], 1);
}

__global__ __launch_bounds__(1024) void k_scan1(
        const int* __restrict__ deg, int* __restrict__ rowptr,
        int* __restrict__ bsum, int n) {
    __shared__ int buf[1024];
    int i = blockIdx.x * 1024 + threadIdx.x;
    int v = (i < n) ? deg[i] : 0;
    buf[threadIdx.x] = v;
    __syncthreads();
    for (int off = 1; off < 1024; off <<= 1) {
        int t = (threadIdx.x >= off) ? buf[threadIdx.x - off] : 0;
        __syncthreads();
        buf[threadIdx.x] += t;
        __syncthreads();
    }
    if (i < n) rowptr[i] = buf[threadIdx.x] - v;
    if (threadIdx.x == 1023) bsum[blockIdx.x] = buf[1023];
}

__global__ __launch_bounds__(128) void k_scan2(int* __restrict__ bsum, int nb) {
    __shared__ int buf[128];
    int v = (threadIdx.x < nb) ? bsum[threadIdx.x] : 0;
    buf[threadIdx.x] = v;
    __syncthreads();
    for (int off = 1; off < 128; off <<= 1) {
        int t = (threadIdx.x >= off) ? buf[threadIdx.x - off] : 0;
        __syncthreads();
        buf[threadIdx.x] += t;
        __syncthreads();
    }
    if (threadIdx.x < nb) bsum[threadIdx.x] = buf[threadIdx.x] - v;
}

__global__ void k_scan3(int* __restrict__ rowptr, const int* __restrict__ bsum,
                        int* __restrict__ cursor, int n, int total) {
    int i = blockIdx.x * 256 + threadIdx.x;
    if (i < n) {
        int v = rowptr[i] + bsum[i >> 10];
        rowptr[i] = v;
        cursor[i] = v;
    }
    if (i == 0) rowptr[n] = total;
}

__global__ void k_fill(const int* __restrict__ src, const int* __restrict__ dst,
                       int* __restrict__ cursor, int* __restrict__ col, int E, int off) {
    int e = blockIdx.x * 256 + threadIdx.x;
    if (e < E) {
        int p = atomicAdd(&cursor[dst[e] + off], 1);
        col[p] = src[e] + off;
    }
}

// ---------------- f32 -> bf16 cast ----------------

__global__ void k_cast_bf(const float* __restrict__ x, u16* __restrict__ o, int n) {
    int i = (blockIdx.x * 256 + threadIdx.x) * 4;
    if (i + 3 < n) {
        float4 v = *(const float4*)&x[i];
        o[i + 0] = f2bf(v.x); o[i + 1] = f2bf(v.y);
        o[i + 2] = f2bf(v.z); o[i + 3] = f2bf(v.w);
    } else {
        for (int j = i; j < n; ++j) o[j] = f2bf(x[j]);
    }
}

// ---------------- weight transpose + cast: W[K,N] f32 -> Wt[N,K] bf16 ----------------

__global__ void k_wt(const float* __restrict__ W, u16* __restrict__ Wt, int K, int N) {
    __shared__ float t[32][33];
    int bn = blockIdx.x * 32;
    int bk = blockIdx.y * 32;
    int x = threadIdx.x;
    int y = threadIdx.y;
    for (int i = y; i < 32; i += 8) t[i][x] = W[(size_t)(bk + i) * N + bn + x];
    __syncthreads();
    for (int i = y; i < 32; i += 8)
        Wt[(size_t)(bn + i) * K + bk + x] = f2bf(t[x][i]);
}

// ---------------- mean aggregation over CSR, bf16 in/out, f32 accum ----------------
// 4-deep software pipeline (round-13 verified)

template<int D>
__global__ __launch_bounds__(256) void k_agg_bf(
        const u16* __restrict__ x, const int* __restrict__ rowptr,
        const int* __restrict__ col, u16* __restrict__ mean, int n) {
    int node = blockIdx.x * 4 + (threadIdx.x >> 6);
    if (node >= n) return;
    int lane = threadIdx.x & 63;
    int s = rowptr[node], e = rowptr[node + 1];
    float inv = (e > s) ? 1.0f / (float)(e - s) : 0.0f;
    if (D == 512) {
        float acc[8] = {};
        const u16* xp = x + lane * 8;
        auto accum = [&](uint4 v) {
            unsigned w[4] = { v.x, v.y, v.z, v.w };
#pragma unroll
            for (int q = 0; q < 4; ++q) {
                acc[2 * q + 0] += bf2f((u16)(w[q] & 0xffff));
                acc[2 * q + 1] += bf2f((u16)(w[q] >> 16));
            }
        };
        int j = s;
        for (; j + 4 <= e; j += 4) {
            int r0 = col[j], r1 = col[j + 1], r2 = col[j + 2], r3 = col[j + 3];
            uint4 v0 = *(const uint4*)(xp + (size_t)r0 * D);
            uint4 v1 = *(const uint4*)(xp + (size_t)r1 * D);
            uint4 v2 = *(const uint4*)(xp + (size_t)r2 * D);
            uint4 v3 = *(const uint4*)(xp + (size_t)r3 * D);
            accum(v0); accum(v1); accum(v2); accum(v3);
        }
        for (; j < e; ++j) {
            int r = col[j];
            accum(*(const uint4*)(xp + (size_t)r * D));
        }
        unsigned o[4];
#pragma unroll
        for (int q = 0; q < 4; ++q)
            o[q] = (unsigned)f2bf(acc[2 * q] * inv) |
                   ((unsigned)f2bf(acc[2 * q + 1] * inv) << 16);
        *(uint4*)(mean + (size_t)node * D + lane * 8) = make_uint4(o[0], o[1], o[2], o[3]);
    } else {  // D == 128
        float a0 = 0.f, a1 = 0.f;
        const u16* xp = x + lane * 2;
        int j = s;
        for (; j + 4 <= e; j += 4) {
            int r0 = col[j], r1 = col[j + 1], r2 = col[j + 2], r3 = col[j + 3];
            unsigned v0 = *(const unsigned*)(xp + (size_t)r0 * D);
            unsigned v1 = *(const unsigned*)(xp + (size_t)r1 * D);
            unsigned v2 = *(const unsigned*)(xp + (size_t)r2 * D);
            unsigned v3 = *(const unsigned*)(xp + (size_t)r3 * D);
            a0 += bf2f((u16)(v0 & 0xffff)) + bf2f((u16)(v1 & 0xffff))
                + bf2f((u16)(v2 & 0xffff)) + bf2f((u16)(v3 & 0xffff));
            a1 += bf2f((u16)(v0 >> 16)) + bf2f((u16)(v1 >> 16))
                + bf2f((u16)(v2 >> 16)) + bf2f((u16)(v3 >> 16));
        }
        for (; j < e; ++j) {
            unsigned v = *(const unsigned*)(xp + (size_t)col[j] * D);
            a0 += bf2f((u16)(v & 0xffff));
            a1 += bf2f((u16)(v >> 16));
        }
        unsigned o = (unsigned)f2bf(a0 * inv) | ((unsigned)f2bf(a1 * inv) << 16);
        *(unsigned*)(mean + (size_t)node * D + lane * 2) = o;
    }
}

#define MFMA_BF16(a, b, c) __builtin_amdgcn_mfma_f32_16x16x32_bf16(a, b, c, 0, 0, 0)

// ---------------- layer-1 fused kernel (round-8, unchanged) ----------------

__global__ __launch_bounds__(256) void k_l1f(
        const u16* __restrict__ X, const u16* __restrict__ Mn,
        const u16* __restrict__ Wr1, const u16* __restrict__ Wl1,
        const u16* __restrict__ Ww,  const u16* __restrict__ Ww2,
        const float* __restrict__ bl1, const float* __restrict__ Wb,
        const float* __restrict__ W2b, const float* __restrict__ prelu_a,
        u16* xin2, u16* xp3, int M) {
    __shared__ __align__(16) char SH[65536];

    int tid = threadIdx.x;
    int wid = tid >> 6, lane = tid & 63;
    int wm = wid >> 1, wn = wid & 1;
    const int lm = lane & 15;
    const int kq = lane >> 4;

    int nwg = gridDim.x;
    int q = nwg >> 3;
    int swz = (blockIdx.x & 7) * q + (blockIdx.x >> 3);
    int m0 = (swz >> 3) * 128;
    int n0 = (swz & 7) * 64;

    f32x4 acch[4][2], accw[4][2], accw2[4][2];
#pragma unroll
    for (int mi = 0; mi < 4; ++mi)
#pragma unroll
        for (int ni = 0; ni < 2; ++ni) {
            acch[mi][ni] = (f32x4){0.f, 0.f, 0.f, 0.f};
            accw[mi][ni] = (f32x4){0.f, 0.f, 0.f, 0.f};
            accw2[mi][ni] = (f32x4){0.f, 0.f, 0.f, 0.f};
        }

    const u16* Bmat[4] = { Wr1, Wl1, Ww, Ww2 };

    auto stage = [&](int buf, int s) {
        int k0 = s * 32;
        char* base = SH + buf * 32768;
#pragma unroll
        for (int i = 0; i < 2; ++i) {
            int f = tid + i * 256;
            int row = f >> 2, g = f & 3;
            int gs = g ^ (row & 3);
            gload16(X + (size_t)(m0 + row) * DIN + k0 + gs * 8,
                    base + i * 4096 + wid * 1024);
        }
#pragma unroll
        for (int i = 0; i < 2; ++i) {
            int f = tid + i * 256;
            int row = f >> 2, g = f & 3;
            int gs = g ^ (row & 3);
            gload16(Mn + (size_t)(m0 + row) * DIN + k0 + gs * 8,
                    base + 8192 + i * 4096 + wid * 1024);
        }
#pragma unroll
        for (int m = 0; m < 4; ++m) {
            int row = tid >> 2, g = tid & 3;
            int gs = g ^ (row & 3);
            gload16(Bmat[m] + (size_t)(n0 + row) * DIN + k0 + gs * 8,
                    base + 16384 + m * 4096 + wid * 1024);
        }
    };

    stage(0, 0);
    __syncthreads();

    int cur = 0;
#pragma unroll 1
    for (int s = 0; s < 4; ++s) {
        if (s + 1 < 4) stage(cur ^ 1, s + 1);

        const char* base = SH + cur * 32768;
        bf16x8 ax[4], am[4];
#pragma unroll
        for (int mi = 0; mi < 4; ++mi) {
            int row = wm * 64 + mi * 16 + lm;
            int g = kq ^ (row & 3);
            ax[mi] = *(const bf16x8*)(base + row * 64 + g * 16);
            am[mi] = *(const bf16x8*)(base + 8192 + row * 64 + g * 16);
        }
#pragma unroll
        for (int m = 0; m < 4; ++m) {
            bf16x8 bfr[2];
#pragma unroll
            for (int ni = 0; ni < 2; ++ni) {
                int row = wn * 32 + ni * 16 + lm;
                int g = kq ^ (row & 3);
                bfr[ni] = *(const bf16x8*)(base + 16384 + m * 4096 + row * 64 + g * 16);
            }
#pragma unroll
            for (int mi = 0; mi < 4; ++mi)
#pragma unroll
                for (int ni = 0; ni < 2; ++ni) {
                    if (m == 0) acch[mi][ni]  = MFMA_BF16(ax[mi], bfr[ni], acch[mi][ni]);
                    if (m == 1) acch[mi][ni]  = MFMA_BF16(am[mi], bfr[ni], acch[mi][ni]);
                    if (m == 2) accw[mi][ni]  = MFMA_BF16(ax[mi], bfr[ni], accw[mi][ni]);
                    if (m == 3) accw2[mi][ni] = MFMA_BF16(ax[mi], bfr[ni], accw2[mi][ni]);
                }
        }
        __syncthreads();
        cur ^= 1;
    }

    float aslope = *prelu_a;
    float blv[2], wbv[2], w2bv[2];
#pragma unroll
    for (int ni = 0; ni < 2; ++ni) {
        int col = n0 + wn * 32 + ni * 16 + lm;
        blv[ni] = bl1[col]; wbv[ni] = Wb[col]; w2bv[ni] = W2b[col];
    }
    char* T = SH + wid * 4608;
#pragma unroll
    for (int pass = 0; pass < 2; ++pass) {
#pragma unroll
        for (int mi = 0; mi < 4; ++mi)
#pragma unroll
            for (int ni = 0; ni < 2; ++ni)
#pragma unroll
                for (int r2 = 0; r2 < 4; ++r2) {
                    float h = acch[mi][ni][r2] + blv[ni];
                    h = (h >= 0.f) ? h : aslope * h;
                    float v = (pass == 0) ? h + accw[mi][ni][r2] + wbv[ni]
                                          : h + accw2[mi][ni][r2] + w2bv[ni];
                    ((u16*)(T + (mi * 16 + kq * 4 + r2) * 72))[ni * 16 + lm] = f2bf(v);
                }
        u16* O = pass ? xp3 : xin2;
#pragma unroll
        for (int it = 0; it < 4; ++it) {
            int lrow = it * 16 + (lane >> 2), seg = lane & 3;
            uint4 d = *(const uint4*)(T + lrow * 72 + seg * 16);
            int grow = m0 + wm * 64 + lrow;
            if (grow < M)
                *(uint4*)(O + (size_t)grow * DH + n0 + wn * 32 + seg * 8) = d;
        }
    }
}

// ---------------- big MFMA GEMM: 128x128 tile, BK=32, 4 waves, 2-phase ----------------
// m97/m103 geometry + coalesced epilogue. 36KB LDS -> 4 blocks/CU; inter-block
// overlap covers the per-K-step vmcnt(0) drain.

template<bool ADDEND, bool OUTF32>
__global__ __launch_bounds__(256, 4) void k_mfma(
        const u16* __restrict__ A1, const u16* __restrict__ B1t,
        const u16* __restrict__ A2, const u16* __restrict__ B2t,
        const float* __restrict__ bias, const u16* addend,
        const float* __restrict__ prelu_a,
        float* Cf, u16* Cb, int M) {
    constexpr int MI = 4;
    // staging: A bufs @0/@8K, B bufs @16K/@24K (32KB); epilogue 4x9216=36KB
    __shared__ __align__(16) char SH[36864];

    constexpr int NS = 32;                      // (512+512)/32

    int tid = threadIdx.x;
    int wid = tid >> 6, lane = tid & 63;
    int wm = wid >> 1, wn = wid & 1;            // 2m x 2n, wave tile 64x64
    const int lm = lane & 15;
    const int kq = lane >> 4;

    int nwg = gridDim.x;                        // 3136, %8==0
    int q = nwg >> 3;
    int swz = (blockIdx.x & 7) * q + (blockIdx.x >> 3);
    int m0 = (swz >> 2) * 128;
    int n0 = (swz & 3) * 128;

    f32x4 acc[MI][4];
#pragma unroll
    for (int mi = 0; mi < MI; ++mi)
#pragma unroll
        for (int ni = 0; ni < 4; ++ni)
            acc[mi][ni] = (f32x4){0.f, 0.f, 0.f, 0.f};

    auto stage = [&](int buf, int s) {
        const u16* A; const u16* Bt; int k0;
        if (s < 16) { A = A1; Bt = B1t; k0 = s * 32; }
        else        { A = A2; Bt = B2t; k0 = (s - 16) * 32; }
#pragma unroll
        for (int i = 0; i < 2; ++i) {           // A: 128 rows x 4 granules = 8KB
            int f = tid + i * 256;
            int row = f >> 2, g = f & 3;
            int gs = g ^ (row & 3);
            gload16(A + (size_t)(m0 + row) * DH + k0 + gs * 8,
                    SH + buf * 8192 + i * 4096 + wid * 1024);
        }
#pragma unroll
        for (int i = 0; i < 2; ++i) {           // B: 128 rows x 4 granules = 8KB
            int f = tid + i * 256;
            int row = f >> 2, g = f & 3;
            int gs = g ^ (row & 3);
            gload16(Bt + (size_t)(n0 + row) * DH + k0 + gs * 8,
                    SH + 16384 + buf * 8192 + i * 4096 + wid * 1024);
        }
    };

    stage(0, 0);
    __syncthreads();

    int cur = 0;
#pragma unroll 1
    for (int s = 0; s < NS; ++s) {
        if (s + 1 < NS) stage(cur ^ 1, s + 1);  // issue next tile early

        const char* Ab = SH + cur * 8192;
        const char* Bb = SH + 16384 + cur * 8192;
        bf16x8 af[MI], bfr[4];
#pragma unroll
        for (int mi = 0; mi < MI; ++mi) {
            int row = wm * 64 + mi * 16 + lm;
            int g = kq ^ (row & 3);
            af[mi] = *(const bf16x8*)(Ab + row * 64 + g * 16);
        }
#pragma unroll
        for (int ni = 0; ni < 4; ++ni) {
            int row = wn * 64 + ni * 16 + lm;
            int g = kq ^ (row & 3);
            bfr[ni] = *(const bf16x8*)(Bb + row * 64 + g * 16);
        }
#pragma unroll
        for (int mi = 0; mi < MI; ++mi)
#pragma unroll
            for (int ni = 0; ni < 4; ++ni)
                acc[mi][ni] = MFMA_BF16(af[mi], bfr[ni], acc[mi][ni]);

        __syncthreads();                        // drains stage(s+1) + barrier
        cur ^= 1;
    }

    // ---- coalesced epilogue via per-wave LDS region (wave tile 64x64) ----
    float aslope = *prelu_a;
    char* EPW = SH + wid * 9216;
    float bv[4];
#pragma unroll
    for (int ni = 0; ni < 4; ++ni)
        bv[ni] = bias[n0 + wn * 64 + ni * 16 + lm];

    if (!OUTF32) {
        u16* T = (u16*)EPW;                     // [64][72] u16
#pragma unroll
        for (int mq = 0; mq < 4; ++mq) {
#pragma unroll
            for (int ni = 0; ni < 4; ++ni)
#pragma unroll
                for (int r2 = 0; r2 < 4; ++r2) {
                    float v = acc[mq][ni][r2] + bv[ni];
                    v = (v >= 0.f) ? v : aslope * v;
                    T[(mq * 16 + kq * 4 + r2) * 72 + ni * 16 + lm] = f2bf(v);
                }
        }
#pragma unroll
        for (int it = 0; it < 8; ++it) {
            int lrow = it * 8 + (lane >> 3);
            int grow = m0 + wm * 64 + lrow;
            uint4 d = *(const uint4*)(T + lrow * 72 + (lane & 7) * 8);
            if (grow < M) {
                size_t off = (size_t)grow * DH + n0 + wn * 64 + (lane & 7) * 8;
                if (ADDEND) {
                    uint4 ad = *(const uint4*)(addend + off);
                    unsigned* dp = (unsigned*)&d;
                    const unsigned* ap = (const unsigned*)&ad;
#pragma unroll
                    for (int qq = 0; qq < 4; ++qq) {
                        float lo = bf2f((u16)(dp[qq] & 0xffff)) + bf2f((u16)(ap[qq] & 0xffff));
                        float hi = bf2f((u16)(dp[qq] >> 16)) + bf2f((u16)(ap[qq] >> 16));
                        dp[qq] = (unsigned)f2bf(lo) | ((unsigned)f2bf(hi) << 16);
                    }
                }
                *(uint4*)(Cb + off) = d;
            }
        }
    } else {
        float* T = (float*)EPW;                 // [32][68] f32 per subpass
#pragma unroll
        for (int sp = 0; sp < 2; ++sp) {
#pragma unroll
            for (int mq = 0; mq < 2; ++mq) {
                int mi = sp * 2 + mq;
#pragma unroll
                for (int ni = 0; ni < 4; ++ni)
#pragma unroll
                    for (int r2 = 0; r2 < 4; ++r2) {
                        float v = acc[mi][ni][r2] + bv[ni];
                        v = (v >= 0.f) ? v : aslope * v;
                        T[(mq * 16 + kq * 4 + r2) * 68 + ni * 16 + lm] = v;
                    }
            }
#pragma unroll
            for (int it = 0; it < 8; ++it) {
                int lrow = it * 4 + (lane >> 4);
                int grow = m0 + wm * 64 + sp * 32 + lrow;
                float4 d = *(const float4*)(T + lrow * 68 + (lane & 15) * 4);
                if (grow < M)
                    *(float4*)(Cf + (size_t)grow * DH + n0 + wn * 64 + (lane & 15) * 4) = d;
            }
        }
    }
}

// ---------------- launch ----------------

extern "C" void kernel_launch(void* const* d_in, const int* in_sizes, int n_in,
                              void* d_out, int out_size, void* d_ws, size_t ws_size,
                              hipStream_t stream) {
    const float* x1 = (const float*)d_in[0];
    const float* x2 = (const float*)d_in[1];
    const int* ei1 = (const int*)d_in[2];
    const int* ei2 = (const int*)d_in[3];
    const float* l1_Wl = (const float*)d_in[4];
    const float* l1_bl = (const float*)d_in[5];
    const float* l1_Wr = (const float*)d_in[6];
    const float* l2_Wl = (const float*)d_in[7];
    const float* l2_bl = (const float*)d_in[8];
    const float* l2_Wr = (const float*)d_in[9];
    const float* l3_Wl = (const float*)d_in[10];
    const float* l3_bl = (const float*)d_in[11];
    const float* l3_Wr = (const float*)d_in[12];
    const float* W_w = (const float*)d_in[13];
    const float* W_b = (const float*)d_in[14];
    const float* W2_w = (const float*)d_in[15];
    const float* W2_b = (const float*)d_in[16];
    const float* prelu_a = (const float*)d_in[17];

    // ---- workspace layout ----
    u16* wb = (u16*)d_ws;
    u16* Wr1t = wb;                        // [512,128]
    u16* Wl1t = Wr1t + 512 * 128;
    u16* Wwt  = Wl1t + 512 * 128;
    u16* W2wt = Wwt  + 512 * 128;
    u16* Wl2t = W2wt + 512 * 128;          // [512,512]
    u16* Wr2t = Wl2t + 512 * 512;
    u16* Wl3t = Wr2t + 512 * 512;
    u16* Wr3t = Wl3t + 512 * 512;
    u16* x_bf    = Wr3t + 512 * 512;               // [MPAD,128]
    u16* mean_bf = x_bf + (size_t)MPAD * DIN;      // [MPAD,512]
    u16* xin2_bf = mean_bf + (size_t)MPAD * DH;    // [MPAD,512]
    u16* xp3_bf  = xin2_bf + (size_t)MPAD * DH;    // [MPAD,512]; xin3 aliases this
    int* iws    = (int*)(xp3_bf + (size_t)MPAD * DH);
    int* deg    = iws;                     // N2
    int* rowptr = iws + N2;                // N2+1
    int* cursor = iws + 2 * N2 + 1;        // N2
    int* bsum   = iws + 3 * N2 + 1;        // 128
    int* colx   = iws + 3 * N2 + 129;      // 2E

    float* out = (float*)d_out;

    // ---- weight transposes (once) ----
    dim3 wtb(32, 8);
    k_wt<<<dim3(16, 4),  wtb, 0, stream>>>(l1_Wr, Wr1t, DIN, DH);
    k_wt<<<dim3(16, 4),  wtb, 0, stream>>>(l1_Wl, Wl1t, DIN, DH);
    k_wt<<<dim3(16, 4),  wtb, 0, stream>>>(W_w,  Wwt,  DIN, DH);
    k_wt<<<dim3(16, 4),  wtb, 0, stream>>>(W2_w, W2wt, DIN, DH);
    k_wt<<<dim3(16, 16), wtb, 0, stream>>>(l2_Wl, Wl2t, DH, DH);
    k_wt<<<dim3(16, 16), wtb, 0, stream>>>(l2_Wr, Wr2t, DH, DH);
    k_wt<<<dim3(16, 16), wtb, 0, stream>>>(l3_Wl, Wl3t, DH, DH);
    k_wt<<<dim3(16, 16), wtb, 0, stream>>>(l3_Wr, Wr3t, DH, DH);

    // ---- batched CSR over 2N nodes (hierarchical scan) ----
    const int NB = (N2 + 1023) / 1024;     // 98
    k_zero_int<<<(N2 + 255) / 256, 256, 0, stream>>>(deg, N2);
    k_deg<<<(NE + 255) / 256, 256, 0, stream>>>(ei1 + NE, deg, NE, 0);
    k_deg<<<(NE + 255) / 256, 256, 0, stream>>>(ei2 + NE, deg, NE, NN);
    k_scan1<<<NB, 1024, 0, stream>>>(deg, rowptr, bsum, N2);
    k_scan2<<<1, 128, 0, stream>>>(bsum, NB);
    k_scan3<<<(N2 + 255) / 256, 256, 0, stream>>>(rowptr, bsum, cursor, N2, E2);
    k_fill<<<(NE + 255) / 256, 256, 0, stream>>>(ei1, ei1 + NE, cursor, colx, NE, 0);
    k_fill<<<(NE + 255) / 256, 256, 0, stream>>>(ei2, ei2 + NE, cursor, colx, NE, NN);

    // ---- features -> bf16 (both graphs into one buffer) ----
    k_cast_bf<<<(NN * DIN / 4 + 255) / 256, 256, 0, stream>>>(x1, x_bf, NN * DIN);
    k_cast_bf<<<(NN * DIN / 4 + 255) / 256, 256, 0, stream>>>(x2, x_bf + (size_t)NN * DIN, NN * DIN);

    const int nwgL1 = (MPAD / 128) * 8;    // 6272
    const int nwgB  = (MPAD / 128) * 4;    // 3136 (128x128 tiles)
    const int aggGrid = (N2 + 3) / 4;      // 25000

    // layer 1: agg(D=128) + fused triple GEMM -> xin2, xp3  (H in registers)
    k_agg_bf<DIN><<<aggGrid, 256, 0, stream>>>(x_bf, rowptr, colx, mean_bf, N2);
    k_l1f<<<nwgL1, 256, 0, stream>>>(x_bf, mean_bf, Wr1t, Wl1t, Wwt, W2wt,
                                     l1_bl, W_b, W2_b, prelu_a, xin2_bf, xp3_bf, N2);

    // layer 2: agg(D=512) + GEMM; xin3 written in-place over xp3 (addend)
    k_agg_bf<DH><<<aggGrid, 256, 0, stream>>>(xin2_bf, rowptr, colx, mean_bf, N2);
    k_mfma<true, false><<<nwgB, 256, 0, stream>>>(
        mean_bf, Wl2t, xin2_bf, Wr2t, l2_bl, xp3_bf, prelu_a, nullptr, xp3_bf, N2);

    // layer 3: agg(D=512) + GEMM -> f32 out (z1|z2 = batched layout)
    k_agg_bf<DH><<<aggGrid, 256, 0, stream>>>(xp3_bf, rowptr, colx, mean_bf, N2);
    k_mfma<false, true><<<nwgB, 256, 0, stream>>>(
        mean_bf, Wl3t, xp3_bf, Wr3t, l3_bl, nullptr, prelu_a, out, nullptr, N2);
}